// Round 9
// baseline (146.687 us; speedup 1.0000x reference)
//
#include <hip/hip_runtime.h>
#include <hip/hip_bf16.h>
#include <cstdint>

// Problem: single attention head, B=4 T=2048 C=1024 H=128, causal, scale = C^-0.5.
// Inputs fp32: x[B,T,C], Wq/Wk/Wv[C,H], mask[T,T] int32 (tril, ignored).
// Output fp32 [B,T,H].
//
// R9: attn v4 -- 32 Q-rows per wave (2 A-frags share K/V frags): 2x arithmetic
// intensity on KV bytes, 1/2 KV traffic, 256 blocks = 1/CU (uniform makespan =
// heaviest block). prep/proj unchanged from R8 (proj's global_load_lds staging
// fixed its MLP bound; it left the top-5).
//   0) prep: convert x->bf16 + transpose W->Wt[3][H][C]
//   1) proj: 64Mx128N/block, BK=64, LDS dbuf via global_load_lds(16B), swizzle
//   2) attn v4: 32-row Q tiles, split-KV-4, ones-column l, K/V prefetch

typedef __bf16 bf16_t;
typedef __bf16 bf16x4 __attribute__((ext_vector_type(4)));
typedef __bf16 bf16x8 __attribute__((ext_vector_type(8)));
typedef float f32x4 __attribute__((ext_vector_type(4)));

#define MFMA16(a, b, c) __builtin_amdgcn_mfma_f32_16x16x32_bf16(a, b, c, 0, 0, 0)

constexpr int T = 2048;
constexpr int C = 1024;
constexpr int H = 128;
constexpr int BK = 64;

__device__ inline bf16x8 load8f(const float* __restrict__ p) {
    float4 a = *(const float4*)p;
    float4 b = *(const float4*)(p + 4);
    bf16x8 r;
    r[0] = (bf16_t)a.x; r[1] = (bf16_t)a.y; r[2] = (bf16_t)a.z; r[3] = (bf16_t)a.w;
    r[4] = (bf16_t)b.x; r[5] = (bf16_t)b.y; r[6] = (bf16_t)b.z; r[7] = (bf16_t)b.w;
    return r;
}

__device__ inline void gld16(const bf16_t* g, bf16_t* l) {
    __builtin_amdgcn_global_load_lds(
        (const __attribute__((address_space(1))) unsigned int*)g,
        (__attribute__((address_space(3))) unsigned int*)l, 16, 0, 0);
}

// ---------------------------------------------------------------------------
// Kernel 0: fused prep. Blocks [0,2048): x fp32->bf16. Blocks [2048,2432):
// W[C][H] -> Wt[z][H][C] bf16 (LDS 32x32 transpose). block 256.
__global__ __launch_bounds__(256) void prep(const float* __restrict__ x,
                                            const float* __restrict__ Wq,
                                            const float* __restrict__ Wk,
                                            const float* __restrict__ Wv,
                                            bf16_t* __restrict__ xb,
                                            bf16_t* __restrict__ Wt) {
    const int t = threadIdx.x;
    if (blockIdx.x < 2048) {
        const int n8 = 4 * T * C / 8;
        int i = blockIdx.x * 256 + t;
        for (; i < n8; i += 2048 * 256)
            *(bf16x8*)(xb + (size_t)i * 8) = load8f(x + (size_t)i * 8);
    } else {
        __shared__ bf16_t tile[32][34];
        const int b2 = blockIdx.x - 2048;
        const int z = b2 >> 7, rem = b2 & 127;
        const int c0 = (rem & 31) * 32, h0 = (rem >> 5) * 32;
        const float* W = z == 0 ? Wq : (z == 1 ? Wk : Wv);
        const int tx = t & 31, ty = t >> 5;
#pragma unroll
        for (int i = 0; i < 4; i++)
            tile[ty + 8 * i][tx] = (bf16_t)W[(size_t)(c0 + ty + 8 * i) * H + h0 + tx];
        __syncthreads();
        bf16_t* Wtz = Wt + (size_t)z * H * C;
#pragma unroll
        for (int i = 0; i < 4; i++)
            Wtz[(size_t)(h0 + ty + 8 * i) * C + c0 + tx] = tile[tx][ty + 8 * i];
    }
}

// ---------------------------------------------------------------------------
// Kernel 1: y = xb @ W (unchanged R8). 64Mx128N/block, BK=64, dbuf LDS via
// global_load_lds(16B), xor swizzle on global side. grid (128,3), block 256.
__global__ __launch_bounds__(256) void proj_gemm(const bf16_t* __restrict__ xb,
                                                 const bf16_t* __restrict__ Wt,
                                                 bf16_t* __restrict__ qout,
                                                 bf16_t* __restrict__ kout,
                                                 bf16_t* __restrict__ vtout) {
    __shared__ __align__(16) bf16_t Ab[2][64 * BK];
    __shared__ __align__(16) bf16_t Bb[2][128 * BK];
    const int t = threadIdx.x;
    const int w = t >> 6, lane = t & 63;
    const int m16 = lane & 15, g = lane >> 4;
    const int wm = w & 1, wn = w >> 1;
    const int z = blockIdx.y;
    const int m0 = blockIdx.x * 64;
    const bf16_t* Bsrc = Wt + (size_t)z * H * C;

    auto stage = [&](int s, int k0) {
#pragma unroll
        for (int i = 0; i < 2; i++) {
            const int e = i * 256 + t;
            const int r = e >> 3, v = e & 7, c8 = v ^ (r & 7);
            gld16(xb + (size_t)(m0 + r) * C + k0 + c8 * 8, &Ab[s][(i * 4 + w) * 512]);
        }
#pragma unroll
        for (int i = 0; i < 4; i++) {
            const int e = i * 256 + t;
            const int r = e >> 3, v = e & 7, c8 = v ^ (r & 7);
            gld16(Bsrc + (size_t)r * C + k0 + c8 * 8, &Bb[s][(i * 4 + w) * 512]);
        }
    };

    f32x4 zero = {0.f, 0.f, 0.f, 0.f};
    f32x4 acc[2][4];
#pragma unroll
    for (int mf = 0; mf < 2; mf++)
#pragma unroll
        for (int nf = 0; nf < 4; nf++) acc[mf][nf] = zero;

    stage(0, 0);
    for (int c = 0; c < C / BK; c++) {
        __syncthreads();
        if (c + 1 < C / BK) stage((c + 1) & 1, (c + 1) * BK);
        const int s = c & 1;

        bf16x8 af[2][2], bfr[4][2];
#pragma unroll
        for (int mf = 0; mf < 2; mf++)
#pragma unroll
            for (int kf = 0; kf < 2; kf++) {
                const int r = wm * 32 + mf * 16 + m16;
                const int v = (kf * 4 + g) ^ (r & 7);
                af[mf][kf] = *(const bf16x8*)(&Ab[s][r * BK + v * 8]);
            }
#pragma unroll
        for (int nf = 0; nf < 4; nf++)
#pragma unroll
            for (int kf = 0; kf < 2; kf++) {
                const int r = wn * 64 + nf * 16 + m16;
                const int v = (kf * 4 + g) ^ (r & 7);
                bfr[nf][kf] = *(const bf16x8*)(&Bb[s][r * BK + v * 8]);
            }
#pragma unroll
        for (int kf = 0; kf < 2; kf++)
#pragma unroll
            for (int mf = 0; mf < 2; mf++)
#pragma unroll
                for (int nf = 0; nf < 4; nf++)
                    acc[mf][nf] = MFMA16(af[mf][kf], bfr[nf][kf], acc[mf][nf]);
    }

    const float sc = (z == 0) ? 0.03125f : 1.0f;
    if (z < 2) {
        bf16_t* out = (z == 0) ? qout : kout;
#pragma unroll
        for (int mf = 0; mf < 2; mf++)
#pragma unroll
            for (int nf = 0; nf < 4; nf++)
#pragma unroll
                for (int ri = 0; ri < 4; ri++) {
                    const int r = m0 + wm * 32 + mf * 16 + g * 4 + ri;
                    const int n = wn * 64 + nf * 16 + m16;
                    out[(size_t)r * H + n] = (bf16_t)(acc[mf][nf][ri] * sc);
                }
    } else {
#pragma unroll
        for (int mf = 0; mf < 2; mf++) {
            const int t0 = m0 + wm * 32 + mf * 16 + g * 4;
            const int bidx = t0 >> 11, tt = t0 & (T - 1);
#pragma unroll
            for (int nf = 0; nf < 4; nf++) {
                const int h = wn * 64 + nf * 16 + m16;
                bf16x4 vv;
#pragma unroll
                for (int ri = 0; ri < 4; ri++) vv[ri] = (bf16_t)acc[mf][nf][ri];
                *(bf16x4*)(vtout + ((size_t)bidx * H + h) * T + tt) = vv;
            }
        }
    }
}

// ---------------------------------------------------------------------------
// Kernel 2: flash attention v4. 32 Q-rows per wave (2 A-frags), causal,
// 4-way in-block KV split, ones-column l, K-prefetch, V before softmax.
// grid (256) = (64 qtiles x 4 b) = 1 block/CU, block 256.
__global__ __launch_bounds__(256, 1) void attn(const bf16_t* __restrict__ q,
                                               const bf16_t* __restrict__ k,
                                               const bf16_t* __restrict__ vt,
                                               float* __restrict__ out) {
    __shared__ float accw[4][32][128];            // 64 KiB
    __shared__ __align__(16) bf16_t pbuf[4][32][40];
    __shared__ float mred[4][32], lred[4][32];
    const int w = threadIdx.x >> 6;
    const int lane = threadIdx.x & 63;
    const int m16 = lane & 15, g = lane >> 4;
    const int b = blockIdx.x & 3;
    const int j = blockIdx.x >> 2;                // 0..63
    const int q0 = j * 32;

    const bf16_t* qb = q + (size_t)b * T * H;
    const bf16_t* kb = k + (size_t)b * T * H;
    const bf16_t* vb = vt + (size_t)b * H * T;

    bf16x8 aq[2][4];
#pragma unroll
    for (int mf = 0; mf < 2; mf++)
#pragma unroll
        for (int c = 0; c < 4; c++)
            aq[mf][c] = *(const bf16x8*)(qb + (size_t)(q0 + mf * 16 + m16) * H + c * 32 + g * 8);

    bf16x8 ones;
#pragma unroll
    for (int i = 0; i < 8; i++) ones[i] = (bf16_t)1.0f;

    f32x4 zero = {0.f, 0.f, 0.f, 0.f};
    f32x4 acc[2][9];                              // [mf][8] = row-sum (l)
#pragma unroll
    for (int mf = 0; mf < 2; mf++)
#pragma unroll
        for (int ht = 0; ht < 9; ht++) acc[mf][ht] = zero;
    float mst[2][4];
#pragma unroll
    for (int mf = 0; mf < 2; mf++)
#pragma unroll
        for (int ri = 0; ri < 4; ri++) mst[mf][ri] = -1e30f;

    const int kv_end = q0 + 32;
    bf16x8 kc[8], kn[8], vc[8];
    int kv0 = w * 32;
    if (kv0 < kv_end) {
#pragma unroll
        for (int t = 0; t < 2; t++)
#pragma unroll
            for (int c = 0; c < 4; c++)
                kc[t * 4 + c] = *(const bf16x8*)(kb + (size_t)(kv0 + t * 16 + m16) * H + c * 32 + g * 8);
    }

    for (; kv0 < kv_end; kv0 += 128) {
        // S[mf][t] = Q K^T (both m-frags share kc)
        f32x4 s[2][2];
#pragma unroll
        for (int mf = 0; mf < 2; mf++) { s[mf][0] = zero; s[mf][1] = zero; }
#pragma unroll
        for (int t = 0; t < 2; t++)
#pragma unroll
            for (int c = 0; c < 4; c++) {
#pragma unroll
                for (int mf = 0; mf < 2; mf++)
                    s[mf][t] = MFMA16(aq[mf][c], kc[t * 4 + c], s[mf][t]);
            }

        // V for current tile (covered by softmax), K for next tile
#pragma unroll
        for (int ht = 0; ht < 8; ht++)
            vc[ht] = *(const bf16x8*)(vb + (size_t)(ht * 16 + m16) * T + kv0 + g * 8);
        const int kvn = kv0 + 128;
        if (kvn < kv_end) {
#pragma unroll
            for (int t = 0; t < 2; t++)
#pragma unroll
                for (int c = 0; c < 4; c++)
                    kn[t * 4 + c] = *(const bf16x8*)(kb + (size_t)(kvn + t * 16 + m16) * H + c * 32 + g * 8);
        }

        // online softmax (q pre-scaled by C^-0.5 in proj)
#pragma unroll
        for (int mf = 0; mf < 2; mf++) {
            float p0v[4], p1v[4];
#pragma unroll
            for (int ri = 0; ri < 4; ri++) {
                const int row = q0 + mf * 16 + g * 4 + ri;
                float v0 = s[mf][0][ri];
                float v1 = s[mf][1][ri];
                if (kv0 + m16 > row) v0 = -1e30f;
                if (kv0 + 16 + m16 > row) v1 = -1e30f;
                float rm = fmaxf(v0, v1);
#pragma unroll
                for (int off = 1; off < 16; off <<= 1) rm = fmaxf(rm, __shfl_xor(rm, off));
                const float mnew = fmaxf(mst[mf][ri], rm);
                const float alpha = __expf(mst[mf][ri] - mnew);
                mst[mf][ri] = mnew;
                p0v[ri] = __expf(v0 - mnew);
                p1v[ri] = __expf(v1 - mnew);
#pragma unroll
                for (int ht = 0; ht < 9; ht++) acc[mf][ht][ri] *= alpha;
            }
#pragma unroll
            for (int ri = 0; ri < 4; ri++) {
                pbuf[w][mf * 16 + g * 4 + ri][m16] = (bf16_t)p0v[ri];
                pbuf[w][mf * 16 + g * 4 + ri][16 + m16] = (bf16_t)p1v[ri];
            }
        }

        // PV (+ ones column for l); both m-frags share vc
#pragma unroll
        for (int mf = 0; mf < 2; mf++) {
            bf16x8 ap = *(const bf16x8*)(&pbuf[w][mf * 16 + m16][g * 8]);
#pragma unroll
            for (int ht = 0; ht < 8; ht++)
                acc[mf][ht] = MFMA16(ap, vc[ht], acc[mf][ht]);
            acc[mf][8] = MFMA16(ap, ones, acc[mf][8]);
        }

#pragma unroll
        for (int i = 0; i < 8; i++) kc[i] = kn[i];
    }

    // ---- cross-wave combine (32 rows) ----
    if (m16 == 0) {
#pragma unroll
        for (int mf = 0; mf < 2; mf++)
#pragma unroll
            for (int ri = 0; ri < 4; ri++)
                mred[w][mf * 16 + g * 4 + ri] = mst[mf][ri];
    }
    __syncthreads();
#pragma unroll
    for (int mf = 0; mf < 2; mf++) {
        float scale[4];
#pragma unroll
        for (int ri = 0; ri < 4; ri++) {
            const int row = mf * 16 + g * 4 + ri;
            float mt = fmaxf(fmaxf(mred[0][row], mred[1][row]),
                             fmaxf(mred[2][row], mred[3][row]));
            scale[ri] = __expf(mst[mf][ri] - mt);
        }
        if (m16 == 0) {
#pragma unroll
            for (int ri = 0; ri < 4; ri++)
                lred[w][mf * 16 + g * 4 + ri] = acc[mf][8][ri] * scale[ri];
        }
#pragma unroll
        for (int ht = 0; ht < 8; ht++)
#pragma unroll
            for (int ri = 0; ri < 4; ri++)
                accw[w][mf * 16 + g * 4 + ri][ht * 16 + m16] = acc[mf][ht][ri] * scale[ri];
    }
    __syncthreads();

    float* ob = out + ((size_t)b * T + q0) * H;
    for (int e = threadIdx.x; e < 32 * 128; e += 256) {
        const int row = e >> 7, col = e & 127;
        float o = accw[0][row][col] + accw[1][row][col] +
                  accw[2][row][col] + accw[3][row][col];
        float l = lred[0][row] + lred[1][row] + lred[2][row] + lred[3][row];
        ob[(size_t)row * H + col] = o / l;
    }
}

// ---------------------------------------------------------------------------
extern "C" void kernel_launch(void* const* d_in, const int* in_sizes, int n_in,
                              void* d_out, int out_size, void* d_ws, size_t ws_size,
                              hipStream_t stream) {
    const float* x = (const float*)d_in[0];
    const float* Wq = (const float*)d_in[1];
    const float* Wk = (const float*)d_in[2];
    const float* Wv = (const float*)d_in[3];
    float* out = (float*)d_out;

    char* ws = (char*)d_ws;
    bf16_t* xb = (bf16_t*)ws;                     // 16 MiB
    bf16_t* Wt = (bf16_t*)(ws + 16777216);        // 768 KiB
    char* p = ws + 16777216 + 786432;
    bf16_t* qb = (bf16_t*)(p);                    // 2 MiB each
    bf16_t* kb = (bf16_t*)(p + 2097152);
    bf16_t* vt = (bf16_t*)(p + 2 * 2097152);      // Vt[B][H][T]

    hipLaunchKernelGGL(prep, dim3(2048 + 384), dim3(256), 0, stream,
                       x, Wq, Wk, Wv, xb, Wt);
    hipLaunchKernelGGL(proj_gemm, dim3(128, 3), dim3(256), 0, stream,
                       xb, Wt, qb, kb, vt);
    hipLaunchKernelGGL(attn, dim3(256), dim3(256), 0, stream,
                       qb, kb, vt, out);
}